// Round 6
// baseline (1009.130 us; speedup 1.0000x reference)
//
#include <hip/hip_runtime.h>

#define N_NODES 50000
#define N_EDGES 800000
#define DIM     128
#define D4      32          // DIM/4 float4 groups
#define NLAYERS 3
#define NATOM   9
#define AVOC    64
#define NBOND   3
#define BVOC    8
#define BN_EPS  1e-5f

// ---------------------------------------------------------------------------
// Atom encoder: h[n][d] = sum_c atom_emb[c][x[n][c]][d]
// ---------------------------------------------------------------------------
__global__ __launch_bounds__(256) void atom_kernel(
    const int* __restrict__ x, const float* __restrict__ ae,
    float* __restrict__ h, int n_nodes)
{
    int tid  = threadIdx.x;
    int lane = tid & 31;
    int node = blockIdx.x * 8 + (tid >> 5);
    if (node >= n_nodes) return;
    const int* xr = x + node * NATOM;
    const float4* ae4 = (const float4*)ae;
    float4 acc = make_float4(0.f, 0.f, 0.f, 0.f);
#pragma unroll
    for (int c = 0; c < NATOM; c++) {
        int v = xr[c];
        float4 t = ae4[(c * AVOC + v) * D4 + lane];
        acc.x += t.x; acc.y += t.y; acc.z += t.z; acc.w += t.w;
    }
    ((float4*)h)[node * D4 + lane] = acc;
}

// ---------------------------------------------------------------------------
// CSR build: histogram -> hierarchical scan -> bucket fill
// ---------------------------------------------------------------------------
__global__ void hist_kernel(const int* __restrict__ dst, int* __restrict__ counts, int n)
{
    int e = blockIdx.x * blockDim.x + threadIdx.x;
    if (e < n) atomicAdd(&counts[dst[e]], 1);
}

// per-block inclusive scan; writes block totals
__global__ __launch_bounds__(256) void scan1_kernel(
    const int* __restrict__ counts, int* __restrict__ incl,
    int* __restrict__ blk_sums, int n)
{
    __shared__ int sh[256];
    int tid = threadIdx.x;
    int i = blockIdx.x * 256 + tid;
    int v = (i < n) ? counts[i] : 0;
    sh[tid] = v;
    __syncthreads();
    for (int off = 1; off < 256; off <<= 1) {
        int t = (tid >= off) ? sh[tid - off] : 0;
        __syncthreads();
        sh[tid] += t;
        __syncthreads();
    }
    if (i < n) incl[i] = sh[tid];
    if (tid == 255) blk_sums[blockIdx.x] = sh[255];
}

// single block: exclusive scan of block sums (nblk <= 256)
__global__ __launch_bounds__(256) void scan2_kernel(int* __restrict__ blk_sums, int nblk)
{
    __shared__ int sh[256];
    int tid = threadIdx.x;
    int v = (tid < nblk) ? blk_sums[tid] : 0;
    sh[tid] = v;
    __syncthreads();
    for (int off = 1; off < 256; off <<= 1) {
        int t = (tid >= off) ? sh[tid - off] : 0;
        __syncthreads();
        sh[tid] += t;
        __syncthreads();
    }
    if (tid < nblk) blk_sums[tid] = sh[tid] - v;   // exclusive
}

// add block offsets, emit row_ptr and cursor
__global__ __launch_bounds__(256) void scan3_kernel(
    const int* __restrict__ counts, const int* __restrict__ incl,
    const int* __restrict__ blk_sums, int* __restrict__ row_ptr,
    int* __restrict__ cursor, int n)
{
    int i = blockIdx.x * 256 + threadIdx.x;
    if (i >= n) return;
    int total = incl[i] + blk_sums[blockIdx.x];
    row_ptr[i + 1] = total;
    cursor[i] = total - counts[i];
    if (i == 0) row_ptr[0] = 0;
}

__global__ void fill_kernel(const int* __restrict__ dst, int* __restrict__ cursor,
                            int* __restrict__ edge_ids, int n)
{
    int e = blockIdx.x * blockDim.x + threadIdx.x;
    if (e < n) { int p = atomicAdd(&cursor[dst[e]], 1); edge_ids[p] = e; }
}

// ---------------------------------------------------------------------------
// Edge aggregation (CSR, no float atomics):
// z[n] = (1+eps)*h[n] + sum_{e: dst==n} relu(h[src[e]] + bond_emb(edge_attr[e]))
// ---------------------------------------------------------------------------
__global__ __launch_bounds__(256) void agg_kernel(
    const float* __restrict__ h, const int* __restrict__ row_ptr,
    const int* __restrict__ edge_ids, const int* __restrict__ src,
    const int* __restrict__ edge_attr, const float* __restrict__ bond_l,
    const float* __restrict__ epsp, float* __restrict__ z, int n_nodes)
{
    __shared__ float4 bt[NBOND * BVOC * D4];   // 12 KB
    int tid = threadIdx.x;
    const float4* b4 = (const float4*)bond_l;
    for (int i = tid; i < NBOND * BVOC * D4; i += 256) bt[i] = b4[i];
    __syncthreads();

    int lane = tid & 31;
    int node = blockIdx.x * 8 + (tid >> 5);
    if (node >= n_nodes) return;

    float eps = epsp[0];
    int j0 = row_ptr[node], j1 = row_ptr[node + 1];
    const float4* h4 = (const float4*)h;
    float4 acc = make_float4(0.f, 0.f, 0.f, 0.f);
    for (int j = j0; j < j1; j++) {
        int e = edge_ids[j];
        int s = src[e];
        const int* ea = edge_attr + e * 3;
        int i0 = ea[0], i1 = ea[1], i2 = ea[2];
        float4 e0 = bt[i0 * D4 + lane];
        float4 e1 = bt[(BVOC + i1) * D4 + lane];
        float4 e2 = bt[(2 * BVOC + i2) * D4 + lane];
        float4 hv = h4[(size_t)s * D4 + lane];
        acc.x += fmaxf(hv.x + e0.x + e1.x + e2.x, 0.f);
        acc.y += fmaxf(hv.y + e0.y + e1.y + e2.y, 0.f);
        acc.z += fmaxf(hv.z + e0.z + e1.z + e2.z, 0.f);
        acc.w += fmaxf(hv.w + e0.w + e1.w + e2.w, 0.f);
    }
    float4 hn = h4[(size_t)node * D4 + lane];
    float s1 = 1.f + eps;
    float4 o;
    o.x = fmaf(s1, hn.x, acc.x);
    o.y = fmaf(s1, hn.y, acc.y);
    o.z = fmaf(s1, hn.z, acc.z);
    o.w = fmaf(s1, hn.w, acc.w);
    ((float4*)z)[(size_t)node * D4 + lane] = o;
}

// ---------------------------------------------------------------------------
// GEMM: out[n] = Aeff[n] @ W + bias, W in LDS (64 KB), 128 rows/block,
// 512 threads: tx=col-group(0..31, 4 cols), ty=row-group(0..15, 8 rows).
// If BN: Aeff = relu(scale*A + shift) applied on load (k-major).
// ---------------------------------------------------------------------------
template <bool BN>
__global__ __launch_bounds__(512, 4) void gemm_kernel(
    const float* __restrict__ A, const float* __restrict__ W,
    const float* __restrict__ bias, const float* __restrict__ scale,
    const float* __restrict__ shift, float* __restrict__ out, int nrows)
{
    __shared__ float Bs[DIM * DIM];  // 64 KB
    __shared__ float scs[DIM], shs[DIM];
    int tid = threadIdx.x;
    {
        float4* Bs4 = (float4*)Bs;
        const float4* W4 = (const float4*)W;
        for (int i = tid; i < DIM * D4; i += 512) Bs4[i] = W4[i];
        if (BN && tid < DIM) { scs[tid] = scale[tid]; shs[tid] = shift[tid]; }
    }
    __syncthreads();

    int tx = tid & 31;
    int ty = tid >> 5;                 // 0..15
    int row0 = blockIdx.x * 128 + ty * 8;

    int ar[8];
#pragma unroll
    for (int r = 0; r < 8; r++) {
        int rr = row0 + r; if (rr > nrows - 1) rr = nrows - 1;
        ar[r] = rr * D4;
    }

    float4 acc[8];
#pragma unroll
    for (int r = 0; r < 8; r++) acc[r] = make_float4(0.f, 0.f, 0.f, 0.f);

    const float4* A4 = (const float4*)A;
    const float4* Bs4 = (const float4*)Bs;
    const float4* sc4p = (const float4*)scs;
    const float4* sh4p = (const float4*)shs;

    for (int k = 0; k < DIM; k += 4) {
        float4 b0 = Bs4[(k + 0) * D4 + tx];
        float4 b1 = Bs4[(k + 1) * D4 + tx];
        float4 b2 = Bs4[(k + 2) * D4 + tx];
        float4 b3 = Bs4[(k + 3) * D4 + tx];
        float4 sc, sf;
        if (BN) { sc = sc4p[k >> 2]; sf = sh4p[k >> 2]; }
#pragma unroll
        for (int r = 0; r < 8; r++) {
            float4 a = A4[ar[r] + (k >> 2)];
            if (BN) {
                a.x = fmaxf(fmaf(a.x, sc.x, sf.x), 0.f);
                a.y = fmaxf(fmaf(a.y, sc.y, sf.y), 0.f);
                a.z = fmaxf(fmaf(a.z, sc.z, sf.z), 0.f);
                a.w = fmaxf(fmaf(a.w, sc.w, sf.w), 0.f);
            }
            acc[r].x = fmaf(a.w, b3.x, fmaf(a.z, b2.x, fmaf(a.y, b1.x, fmaf(a.x, b0.x, acc[r].x))));
            acc[r].y = fmaf(a.w, b3.y, fmaf(a.z, b2.y, fmaf(a.y, b1.y, fmaf(a.x, b0.y, acc[r].y))));
            acc[r].z = fmaf(a.w, b3.z, fmaf(a.z, b2.z, fmaf(a.y, b1.z, fmaf(a.x, b0.z, acc[r].z))));
            acc[r].w = fmaf(a.w, b3.w, fmaf(a.z, b2.w, fmaf(a.y, b1.w, fmaf(a.x, b0.w, acc[r].w))));
        }
    }

    float4 bv = ((const float4*)bias)[tx];
    float4* out4 = (float4*)out;
#pragma unroll
    for (int r = 0; r < 8; r++) {
        int row = row0 + r;
        if (row < nrows) {
            float4 o;
            o.x = acc[r].x + bv.x; o.y = acc[r].y + bv.y;
            o.z = acc[r].z + bv.z; o.w = acc[r].w + bv.w;
            out4[(size_t)row * D4 + tx] = o;
        }
    }
}

// ---------------------------------------------------------------------------
// Column stats: per-column sum and sum of squares (training-mode BN).
// ---------------------------------------------------------------------------
__global__ __launch_bounds__(128) void stats_kernel(
    const float* __restrict__ X, int nrows,
    float* __restrict__ sum_out, float* __restrict__ ssq_out)
{
    int c = threadIdx.x;
    float s = 0.f, q = 0.f;
    for (int r = blockIdx.x; r < nrows; r += gridDim.x) {
        float v = X[(size_t)r * DIM + c];
        s += v;
        q = fmaf(v, v, q);
    }
    atomicAdd(&sum_out[c], s);
    atomicAdd(&ssq_out[c], q);
}

__global__ void coef_kernel(const float* __restrict__ sum, const float* __restrict__ ssq,
                            const float* __restrict__ gamma, const float* __restrict__ beta,
                            float* __restrict__ scale, float* __restrict__ shift, float inv_n)
{
    int c = threadIdx.x;
    float mu = sum[c] * inv_n;
    float var = ssq[c] * inv_n - mu * mu;
    if (var < 0.f) var = 0.f;
    float sc = gamma[c] * rsqrtf(var + BN_EPS);
    scale[c] = sc;
    shift[c] = fmaf(-mu, sc, beta[c]);
}

// ---------------------------------------------------------------------------
// Elementwise BN apply (+ optional relu): out = scale*X + shift
// ---------------------------------------------------------------------------
__global__ __launch_bounds__(256) void apply_kernel(
    const float* __restrict__ X, const float* __restrict__ scale,
    const float* __restrict__ shift, float* __restrict__ out, int n4, int relu)
{
    int i = blockIdx.x * blockDim.x + threadIdx.x;
    if (i >= n4) return;
    int c4 = i & 31;
    float4 v = ((const float4*)X)[i];
    float4 sc = ((const float4*)scale)[c4];
    float4 sf = ((const float4*)shift)[c4];
    v.x = fmaf(v.x, sc.x, sf.x);
    v.y = fmaf(v.y, sc.y, sf.y);
    v.z = fmaf(v.z, sc.z, sf.z);
    v.w = fmaf(v.w, sc.w, sf.w);
    if (relu) {
        v.x = fmaxf(v.x, 0.f); v.y = fmaxf(v.y, 0.f);
        v.z = fmaxf(v.z, 0.f); v.w = fmaxf(v.w, 0.f);
    }
    ((float4*)out)[i] = v;
}

// ---------------------------------------------------------------------------
extern "C" void kernel_launch(void* const* d_in, const int* in_sizes, int n_in,
                              void* d_out, int out_size, void* d_ws, size_t ws_size,
                              hipStream_t stream)
{
    const int*   x         = (const int*)d_in[0];
    const int*   edge_attr = (const int*)d_in[1];
    const int*   src       = (const int*)d_in[2];
    const int*   dst       = (const int*)d_in[3];
    const float* atom_emb  = (const float*)d_in[4];
    const float* bond_emb  = (const float*)d_in[5];
    const float* W1        = (const float*)d_in[6];
    const float* b1        = (const float*)d_in[7];
    const float* g1        = (const float*)d_in[8];
    const float* be1       = (const float*)d_in[9];
    const float* W2        = (const float*)d_in[10];
    const float* b2        = (const float*)d_in[11];
    const float* gin_eps   = (const float*)d_in[12];
    const float* og        = (const float*)d_in[13];
    const float* ob        = (const float*)d_in[14];
    float* out = (float*)d_out;

    const size_t ND = (size_t)N_NODES * DIM;
    const int NBLK = (N_NODES + 255) / 256;   // 196

    // workspace layout (stats first: 16B-aligned float4 reads everywhere)
    float* stats = (float*)d_ws;            // 1024 floats
    float* h  = stats + 1024;
    float* z  = h + ND;
    float* z1 = out;                        // alias: d_out doubles as scratch
    int* counts   = (int*)(z + ND);
    int* row_ptr  = counts + N_NODES;
    int* cursor   = row_ptr + N_NODES + 1;
    int* edge_ids = cursor + N_NODES;
    int* incl     = edge_ids + N_EDGES;
    int* blk_sums = incl + N_NODES;         // NBLK ints

    float* sum1 = stats,        *ssq1 = stats + 128;
    float* sum2 = stats + 256,  *ssq2 = stats + 384;
    float* sc1  = stats + 512,  *sh1  = stats + 640;
    float* sc2  = stats + 768,  *sh2  = stats + 896;

    hipMemsetAsync(counts, 0, N_NODES * sizeof(int), stream);
    atom_kernel<<<(N_NODES + 7) / 8, 256, 0, stream>>>(x, atom_emb, h, N_NODES);
    hist_kernel<<<(N_EDGES + 255) / 256, 256, 0, stream>>>(dst, counts, N_EDGES);
    scan1_kernel<<<NBLK, 256, 0, stream>>>(counts, incl, blk_sums, N_NODES);
    scan2_kernel<<<1, 256, 0, stream>>>(blk_sums, NBLK);
    scan3_kernel<<<NBLK, 256, 0, stream>>>(counts, incl, blk_sums, row_ptr, cursor, N_NODES);
    fill_kernel<<<(N_EDGES + 255) / 256, 256, 0, stream>>>(dst, cursor, edge_ids, N_EDGES);

    const float inv_n = 1.0f / (float)N_NODES;
    for (int l = 0; l < NLAYERS; l++) {
        const float* bond_l = bond_emb + (size_t)l * NBOND * BVOC * DIM;
        hipMemsetAsync(stats, 0, 512 * sizeof(float), stream);
        agg_kernel<<<(N_NODES + 7) / 8, 256, 0, stream>>>(
            h, row_ptr, edge_ids, src, edge_attr, bond_l, gin_eps + l, z, N_NODES);
        gemm_kernel<false><<<(N_NODES + 127) / 128, 512, 0, stream>>>(
            z, W1 + (size_t)l * DIM * DIM, b1 + l * DIM, nullptr, nullptr, z1, N_NODES);
        stats_kernel<<<512, 128, 0, stream>>>(z1, N_NODES, sum1, ssq1);
        coef_kernel<<<1, 128, 0, stream>>>(sum1, ssq1, g1 + l * DIM, be1 + l * DIM, sc1, sh1, inv_n);
        gemm_kernel<true><<<(N_NODES + 127) / 128, 512, 0, stream>>>(
            z1, W2 + (size_t)l * DIM * DIM, b2 + l * DIM, sc1, sh1, z, N_NODES);
        stats_kernel<<<512, 128, 0, stream>>>(z, N_NODES, sum2, ssq2);
        coef_kernel<<<1, 128, 0, stream>>>(sum2, ssq2, og + l * DIM, ob + l * DIM, sc2, sh2, inv_n);
        float* tgt = (l < NLAYERS - 1) ? h : out;
        apply_kernel<<<((int)(N_NODES * D4) + 255) / 256, 256, 0, stream>>>(
            z, sc2, sh2, tgt, N_NODES * D4, (l < NLAYERS - 1) ? 1 : 0);
    }
}

// Round 12
// 792.116 us; speedup vs baseline: 1.2740x; 1.2740x over previous
//
#include <hip/hip_runtime.h>

#define N_NODES 50000
#define N_EDGES 800000
#define DIM     128
#define D4      32          // DIM/4 float4 groups
#define NLAYERS 3
#define NATOM   9
#define AVOC    64
#define NBOND   3
#define BVOC    8
#define BN_EPS  1e-5f
#define INVN    (1.0f / (float)N_NODES)

// ---------------------------------------------------------------------------
// Atom encoder: h[n][d] = sum_c atom_emb[c][x[n][c]][d]
// ---------------------------------------------------------------------------
__global__ __launch_bounds__(256) void atom_kernel(
    const int* __restrict__ x, const float* __restrict__ ae,
    float* __restrict__ h, int n_nodes)
{
    int tid  = threadIdx.x;
    int lane = tid & 31;
    int node = blockIdx.x * 8 + (tid >> 5);
    if (node >= n_nodes) return;
    const int* xr = x + node * NATOM;
    const float4* ae4 = (const float4*)ae;
    float4 acc = make_float4(0.f, 0.f, 0.f, 0.f);
#pragma unroll
    for (int c = 0; c < NATOM; c++) {
        int v = xr[c];
        float4 t = ae4[(c * AVOC + v) * D4 + lane];
        acc.x += t.x; acc.y += t.y; acc.z += t.z; acc.w += t.w;
    }
    ((float4*)h)[node * D4 + lane] = acc;
}

// ---------------------------------------------------------------------------
// CSR build: histogram -> hierarchical scan -> bucket fill (src+bond packed)
// ---------------------------------------------------------------------------
__global__ void hist_kernel(const int* __restrict__ dst, int* __restrict__ counts, int n)
{
    int e = blockIdx.x * blockDim.x + threadIdx.x;
    if (e < n) atomicAdd(&counts[dst[e]], 1);
}

__global__ __launch_bounds__(256) void scan1_kernel(
    const int* __restrict__ counts, int* __restrict__ incl,
    int* __restrict__ blk_sums, int n)
{
    __shared__ int sh[256];
    int tid = threadIdx.x;
    int i = blockIdx.x * 256 + tid;
    int v = (i < n) ? counts[i] : 0;
    sh[tid] = v;
    __syncthreads();
    for (int off = 1; off < 256; off <<= 1) {
        int t = (tid >= off) ? sh[tid - off] : 0;
        __syncthreads();
        sh[tid] += t;
        __syncthreads();
    }
    if (i < n) incl[i] = sh[tid];
    if (tid == 255) blk_sums[blockIdx.x] = sh[255];
}

__global__ __launch_bounds__(256) void scan2_kernel(int* __restrict__ blk_sums, int nblk)
{
    __shared__ int sh[256];
    int tid = threadIdx.x;
    int v = (tid < nblk) ? blk_sums[tid] : 0;
    sh[tid] = v;
    __syncthreads();
    for (int off = 1; off < 256; off <<= 1) {
        int t = (tid >= off) ? sh[tid - off] : 0;
        __syncthreads();
        sh[tid] += t;
        __syncthreads();
    }
    if (tid < nblk) blk_sums[tid] = sh[tid] - v;   // exclusive
}

__global__ __launch_bounds__(256) void scan3_kernel(
    const int* __restrict__ counts, const int* __restrict__ incl,
    const int* __restrict__ blk_sums, int* __restrict__ row_ptr,
    int* __restrict__ cursor, int n)
{
    int i = blockIdx.x * 256 + threadIdx.x;
    if (i >= n) return;
    int total = incl[i] + blk_sums[blockIdx.x];
    row_ptr[i + 1] = total;
    cursor[i] = total - counts[i];
    if (i == 0) row_ptr[0] = 0;
}

// fill: store src and packed bond indices at the CSR slot (kills one
// indirection level in agg: no edge_ids->src/edge_attr chase)
__global__ void fill_kernel(const int* __restrict__ dst, const int* __restrict__ src,
                            const int* __restrict__ edge_attr, int* __restrict__ cursor,
                            int* __restrict__ esrc, int* __restrict__ ebond, int n)
{
    int e = blockIdx.x * blockDim.x + threadIdx.x;
    if (e >= n) return;
    int p = atomicAdd(&cursor[dst[e]], 1);
    esrc[p] = src[e];
    const int* ea = edge_attr + e * 3;
    ebond[p] = ea[0] | (ea[1] << 8) | (ea[2] << 16);
}

// ---------------------------------------------------------------------------
// Edge aggregation (CSR, no float atomics). Optionally applies the previous
// layer's outer-BN (+ReLU) to its input on the fly (coefs from raw sums):
//   h_eff = BNIN ? relu(sc*zin + sf) : zin
//   z[n] = (1+eps)*h_eff[n] + sum_{e: dst==n} relu(h_eff[src] + bond_emb)
// ---------------------------------------------------------------------------
template <bool BNIN>
__global__ __launch_bounds__(256) void agg_kernel(
    const float* __restrict__ zin, const int* __restrict__ row_ptr,
    const int* __restrict__ esrc, const int* __restrict__ ebond,
    const float* __restrict__ bond_l, const float* __restrict__ epsp,
    const float* __restrict__ sum2p, const float* __restrict__ ssq2p,
    const float* __restrict__ gam, const float* __restrict__ bet,
    float* __restrict__ z, int n_nodes)
{
    __shared__ float4 bt[NBOND * BVOC * D4];   // 12 KB
    int tid = threadIdx.x;
    const float4* b4 = (const float4*)bond_l;
    for (int i = tid; i < NBOND * BVOC * D4; i += 256) bt[i] = b4[i];
    __syncthreads();

    int lane = tid & 31;
    int node = blockIdx.x * 8 + (tid >> 5);
    if (node >= n_nodes) return;

    // per-lane BN coefs for this lane's 4 columns
    float4 sc = make_float4(1.f, 1.f, 1.f, 1.f);
    float4 sf = make_float4(0.f, 0.f, 0.f, 0.f);
    if (BNIN) {
        float4 sm = ((const float4*)sum2p)[lane];
        float4 sq = ((const float4*)ssq2p)[lane];
        float4 g  = ((const float4*)gam)[lane];
        float4 b  = ((const float4*)bet)[lane];
        float mux = sm.x * INVN, muy = sm.y * INVN, muz = sm.z * INVN, muw = sm.w * INVN;
        float vx = fmaxf(sq.x * INVN - mux * mux, 0.f);
        float vy = fmaxf(sq.y * INVN - muy * muy, 0.f);
        float vz = fmaxf(sq.z * INVN - muz * muz, 0.f);
        float vw = fmaxf(sq.w * INVN - muw * muw, 0.f);
        sc.x = g.x * rsqrtf(vx + BN_EPS); sc.y = g.y * rsqrtf(vy + BN_EPS);
        sc.z = g.z * rsqrtf(vz + BN_EPS); sc.w = g.w * rsqrtf(vw + BN_EPS);
        sf.x = fmaf(-mux, sc.x, b.x); sf.y = fmaf(-muy, sc.y, b.y);
        sf.z = fmaf(-muz, sc.z, b.z); sf.w = fmaf(-muw, sc.w, b.w);
    }

    float eps = epsp[0];
    int j0 = row_ptr[node], j1 = row_ptr[node + 1];
    const float4* zin4 = (const float4*)zin;
    float4 acc = make_float4(0.f, 0.f, 0.f, 0.f);

#define HEFF(v) do { if (BNIN) { \
        (v).x = fmaxf(fmaf((v).x, sc.x, sf.x), 0.f); \
        (v).y = fmaxf(fmaf((v).y, sc.y, sf.y), 0.f); \
        (v).z = fmaxf(fmaf((v).z, sc.z, sf.z), 0.f); \
        (v).w = fmaxf(fmaf((v).w, sc.w, sf.w), 0.f); } } while (0)

    int j = j0;
    for (; j + 2 <= j1; j += 2) {
        int s0 = esrc[j],     bb0 = ebond[j];
        int s1 = esrc[j + 1], bb1 = ebond[j + 1];
        float4 h0 = zin4[(size_t)s0 * D4 + lane];
        float4 h1 = zin4[(size_t)s1 * D4 + lane];
        float4 a0 = bt[(bb0 & 255) * D4 + lane];
        float4 a1 = bt[(BVOC + ((bb0 >> 8) & 255)) * D4 + lane];
        float4 a2 = bt[(2 * BVOC + ((bb0 >> 16) & 255)) * D4 + lane];
        float4 c0 = bt[(bb1 & 255) * D4 + lane];
        float4 c1 = bt[(BVOC + ((bb1 >> 8) & 255)) * D4 + lane];
        float4 c2 = bt[(2 * BVOC + ((bb1 >> 16) & 255)) * D4 + lane];
        HEFF(h0); HEFF(h1);
        acc.x += fmaxf(h0.x + a0.x + a1.x + a2.x, 0.f) + fmaxf(h1.x + c0.x + c1.x + c2.x, 0.f);
        acc.y += fmaxf(h0.y + a0.y + a1.y + a2.y, 0.f) + fmaxf(h1.y + c0.y + c1.y + c2.y, 0.f);
        acc.z += fmaxf(h0.z + a0.z + a1.z + a2.z, 0.f) + fmaxf(h1.z + c0.z + c1.z + c2.z, 0.f);
        acc.w += fmaxf(h0.w + a0.w + a1.w + a2.w, 0.f) + fmaxf(h1.w + c0.w + c1.w + c2.w, 0.f);
    }
    if (j < j1) {
        int s0 = esrc[j], bb0 = ebond[j];
        float4 h0 = zin4[(size_t)s0 * D4 + lane];
        float4 a0 = bt[(bb0 & 255) * D4 + lane];
        float4 a1 = bt[(BVOC + ((bb0 >> 8) & 255)) * D4 + lane];
        float4 a2 = bt[(2 * BVOC + ((bb0 >> 16) & 255)) * D4 + lane];
        HEFF(h0);
        acc.x += fmaxf(h0.x + a0.x + a1.x + a2.x, 0.f);
        acc.y += fmaxf(h0.y + a0.y + a1.y + a2.y, 0.f);
        acc.z += fmaxf(h0.z + a0.z + a1.z + a2.z, 0.f);
        acc.w += fmaxf(h0.w + a0.w + a1.w + a2.w, 0.f);
    }

    float4 hn = zin4[(size_t)node * D4 + lane];
    HEFF(hn);
#undef HEFF
    float s1v = 1.f + eps;
    float4 o;
    o.x = fmaf(s1v, hn.x, acc.x);
    o.y = fmaf(s1v, hn.y, acc.y);
    o.z = fmaf(s1v, hn.z, acc.z);
    o.w = fmaf(s1v, hn.w, acc.w);
    ((float4*)z)[(size_t)node * D4 + lane] = o;
}

// ---------------------------------------------------------------------------
// GEMM + fused column-stats epilogue. W in LDS (64 KB), 128 rows/block,
// 512 threads: tx=col-group(0..31, 4 cols), ty=row-group(0..15, 8 rows).
// If BN: A_eff = relu(scale*A + shift), coefs computed inline from raw sums.
// Epilogue: block-reduced column sum / sumsq atomically added to sum/ssq.
// ---------------------------------------------------------------------------
template <bool BN>
__global__ __launch_bounds__(512, 4) void gemm_kernel(
    const float* __restrict__ A, const float* __restrict__ W,
    const float* __restrict__ bias,
    const float* __restrict__ sum_in, const float* __restrict__ ssq_in,
    const float* __restrict__ gam, const float* __restrict__ bet,
    float* __restrict__ sum_out, float* __restrict__ ssq_out,
    float* __restrict__ out, int nrows)
{
    __shared__ float Bs[DIM * DIM];  // 64 KB (reused for stats reduction)
    __shared__ float scs[DIM], shs[DIM];
    int tid = threadIdx.x;
    {
        float4* Bs4 = (float4*)Bs;
        const float4* W4 = (const float4*)W;
        for (int i = tid; i < DIM * D4; i += 512) Bs4[i] = W4[i];
        if (BN && tid < DIM) {
            float mu = sum_in[tid] * INVN;
            float var = fmaxf(ssq_in[tid] * INVN - mu * mu, 0.f);
            float sc = gam[tid] * rsqrtf(var + BN_EPS);
            scs[tid] = sc;
            shs[tid] = fmaf(-mu, sc, bet[tid]);
        }
    }
    __syncthreads();

    int tx = tid & 31;
    int ty = tid >> 5;                 // 0..15
    int row0 = blockIdx.x * 128 + ty * 8;

    int ar[8];
#pragma unroll
    for (int r = 0; r < 8; r++) {
        int rr = row0 + r; if (rr > nrows - 1) rr = nrows - 1;
        ar[r] = rr * D4;
    }

    float4 acc[8];
#pragma unroll
    for (int r = 0; r < 8; r++) acc[r] = make_float4(0.f, 0.f, 0.f, 0.f);

    const float4* A4 = (const float4*)A;
    const float4* Bs4 = (const float4*)Bs;
    const float4* sc4p = (const float4*)scs;
    const float4* sh4p = (const float4*)shs;

    for (int k = 0; k < DIM; k += 4) {
        float4 b0 = Bs4[(k + 0) * D4 + tx];
        float4 b1 = Bs4[(k + 1) * D4 + tx];
        float4 b2 = Bs4[(k + 2) * D4 + tx];
        float4 b3 = Bs4[(k + 3) * D4 + tx];
        float4 sc, sf;
        if (BN) { sc = sc4p[k >> 2]; sf = sh4p[k >> 2]; }
#pragma unroll
        for (int r = 0; r < 8; r++) {
            float4 a = A4[ar[r] + (k >> 2)];
            if (BN) {
                a.x = fmaxf(fmaf(a.x, sc.x, sf.x), 0.f);
                a.y = fmaxf(fmaf(a.y, sc.y, sf.y), 0.f);
                a.z = fmaxf(fmaf(a.z, sc.z, sf.z), 0.f);
                a.w = fmaxf(fmaf(a.w, sc.w, sf.w), 0.f);
            }
            acc[r].x = fmaf(a.w, b3.x, fmaf(a.z, b2.x, fmaf(a.y, b1.x, fmaf(a.x, b0.x, acc[r].x))));
            acc[r].y = fmaf(a.w, b3.y, fmaf(a.z, b2.y, fmaf(a.y, b1.y, fmaf(a.x, b0.y, acc[r].y))));
            acc[r].z = fmaf(a.w, b3.z, fmaf(a.z, b2.z, fmaf(a.y, b1.z, fmaf(a.x, b0.z, acc[r].z))));
            acc[r].w = fmaf(a.w, b3.w, fmaf(a.z, b2.w, fmaf(a.y, b1.w, fmaf(a.x, b0.w, acc[r].w))));
        }
    }

    float4 bv = ((const float4*)bias)[tx];
    float4* out4 = (float4*)out;
    float4 s4 = make_float4(0.f, 0.f, 0.f, 0.f);
    float4 q4 = make_float4(0.f, 0.f, 0.f, 0.f);
#pragma unroll
    for (int r = 0; r < 8; r++) {
        int row = row0 + r;
        if (row < nrows) {
            float4 o;
            o.x = acc[r].x + bv.x; o.y = acc[r].y + bv.y;
            o.z = acc[r].z + bv.z; o.w = acc[r].w + bv.w;
            out4[(size_t)row * D4 + tx] = o;
            s4.x += o.x; s4.y += o.y; s4.z += o.z; s4.w += o.w;
            q4.x = fmaf(o.x, o.x, q4.x); q4.y = fmaf(o.y, o.y, q4.y);
            q4.z = fmaf(o.z, o.z, q4.z); q4.w = fmaf(o.w, o.w, q4.w);
        }
    }

    // block-wide column reduction in (reused) Bs, then one atomic set per block
    __syncthreads();
    float4* red = (float4*)Bs;          // 1024 float4 capacity; we use 2x512
    red[tid] = s4;
    red[512 + tid] = q4;
    __syncthreads();
#pragma unroll
    for (int off = 256; off >= 32; off >>= 1) {
        if (tid < off) {
            float4 a = red[tid], b = red[tid + off];
            a.x += b.x; a.y += b.y; a.z += b.z; a.w += b.w;
            red[tid] = a;
            float4 c = red[512 + tid], d = red[512 + tid + off];
            c.x += d.x; c.y += d.y; c.z += d.z; c.w += d.w;
            red[512 + tid] = c;
        }
        __syncthreads();
    }
    if (tid < 32) {
        float4 s = red[tid], q = red[512 + tid];
        atomicAdd(&sum_out[tid * 4 + 0], s.x);
        atomicAdd(&sum_out[tid * 4 + 1], s.y);
        atomicAdd(&sum_out[tid * 4 + 2], s.z);
        atomicAdd(&sum_out[tid * 4 + 3], s.w);
        atomicAdd(&ssq_out[tid * 4 + 0], q.x);
        atomicAdd(&ssq_out[tid * 4 + 1], q.y);
        atomicAdd(&ssq_out[tid * 4 + 2], q.z);
        atomicAdd(&ssq_out[tid * 4 + 3], q.w);
    }
}

// ---------------------------------------------------------------------------
// Final BN apply (no relu), coefs computed inline from raw sums.
// ---------------------------------------------------------------------------
__global__ __launch_bounds__(256) void apply_final_kernel(
    const float* __restrict__ X, const float* __restrict__ sum2,
    const float* __restrict__ ssq2, const float* __restrict__ gam,
    const float* __restrict__ bet, float* __restrict__ out, int n4)
{
    int i = blockIdx.x * blockDim.x + threadIdx.x;
    if (i >= n4) return;
    int c4 = i & 31;
    float4 sm = ((const float4*)sum2)[c4];
    float4 sq = ((const float4*)ssq2)[c4];
    float4 g  = ((const float4*)gam)[c4];
    float4 b  = ((const float4*)bet)[c4];
    float mux = sm.x * INVN, muy = sm.y * INVN, muz = sm.z * INVN, muw = sm.w * INVN;
    float4 sc, sf;
    sc.x = g.x * rsqrtf(fmaxf(sq.x * INVN - mux * mux, 0.f) + BN_EPS);
    sc.y = g.y * rsqrtf(fmaxf(sq.y * INVN - muy * muy, 0.f) + BN_EPS);
    sc.z = g.z * rsqrtf(fmaxf(sq.z * INVN - muz * muz, 0.f) + BN_EPS);
    sc.w = g.w * rsqrtf(fmaxf(sq.w * INVN - muw * muw, 0.f) + BN_EPS);
    sf.x = fmaf(-mux, sc.x, b.x); sf.y = fmaf(-muy, sc.y, b.y);
    sf.z = fmaf(-muz, sc.z, b.z); sf.w = fmaf(-muw, sc.w, b.w);
    float4 v = ((const float4*)X)[i];
    v.x = fmaf(v.x, sc.x, sf.x);
    v.y = fmaf(v.y, sc.y, sf.y);
    v.z = fmaf(v.z, sc.z, sf.z);
    v.w = fmaf(v.w, sc.w, sf.w);
    ((float4*)out)[i] = v;
}

// ---------------------------------------------------------------------------
extern "C" void kernel_launch(void* const* d_in, const int* in_sizes, int n_in,
                              void* d_out, int out_size, void* d_ws, size_t ws_size,
                              hipStream_t stream)
{
    const int*   x         = (const int*)d_in[0];
    const int*   edge_attr = (const int*)d_in[1];
    const int*   src       = (const int*)d_in[2];
    const int*   dst       = (const int*)d_in[3];
    const float* atom_emb  = (const float*)d_in[4];
    const float* bond_emb  = (const float*)d_in[5];
    const float* W1        = (const float*)d_in[6];
    const float* b1        = (const float*)d_in[7];
    const float* g1        = (const float*)d_in[8];
    const float* be1       = (const float*)d_in[9];
    const float* W2        = (const float*)d_in[10];
    const float* b2        = (const float*)d_in[11];
    const float* gin_eps   = (const float*)d_in[12];
    const float* og        = (const float*)d_in[13];
    const float* ob        = (const float*)d_in[14];
    float* out = (float*)d_out;

    const size_t ND = (size_t)N_NODES * DIM;
    const int NBLK = (N_NODES + 255) / 256;   // 196

    // workspace layout: per-layer stats first (16B alignment preserved)
    // stats layer l: [l*512+0..127]=sum1, +128 ssq1, +256 sum2, +384 ssq2
    float* stats = (float*)d_ws;            // 2048 floats reserved
    float* zagg  = stats + 2048;            // agg output
    float* z2buf = zagg + ND;               // atom output & gemm2 output
    float* z1    = out;                     // gemm1 output aliases d_out
    int* counts   = (int*)(z2buf + ND);
    int* row_ptr  = counts + N_NODES;
    int* cursor   = row_ptr + N_NODES + 1;
    int* esrc     = cursor + N_NODES;
    int* ebond    = esrc + N_EDGES;
    int* incl     = ebond + N_EDGES;
    int* blk_sums = incl + N_NODES;         // NBLK ints

    hipMemsetAsync(counts, 0, N_NODES * sizeof(int), stream);
    hipMemsetAsync(stats, 0, 1536 * sizeof(float), stream);
    atom_kernel<<<(N_NODES + 7) / 8, 256, 0, stream>>>(x, atom_emb, z2buf, N_NODES);
    hist_kernel<<<(N_EDGES + 255) / 256, 256, 0, stream>>>(dst, counts, N_EDGES);
    scan1_kernel<<<NBLK, 256, 0, stream>>>(counts, incl, blk_sums, N_NODES);
    scan2_kernel<<<1, 256, 0, stream>>>(blk_sums, NBLK);
    scan3_kernel<<<NBLK, 256, 0, stream>>>(counts, incl, blk_sums, row_ptr, cursor, N_NODES);
    fill_kernel<<<(N_EDGES + 255) / 256, 256, 0, stream>>>(dst, src, edge_attr, cursor,
                                                           esrc, ebond, N_EDGES);

    for (int l = 0; l < NLAYERS; l++) {
        const float* bond_l = bond_emb + (size_t)l * NBOND * BVOC * DIM;
        float* st   = stats + (size_t)l * 512;
        float* sum1 = st,       *ssq1 = st + 128;
        float* sum2 = st + 256, *ssq2 = st + 384;

        if (l == 0) {
            agg_kernel<false><<<(N_NODES + 7) / 8, 256, 0, stream>>>(
                z2buf, row_ptr, esrc, ebond, bond_l, gin_eps + l,
                nullptr, nullptr, nullptr, nullptr, zagg, N_NODES);
        } else {
            float* stp = stats + (size_t)(l - 1) * 512;
            agg_kernel<true><<<(N_NODES + 7) / 8, 256, 0, stream>>>(
                z2buf, row_ptr, esrc, ebond, bond_l, gin_eps + l,
                stp + 256, stp + 384, og + (l - 1) * DIM, ob + (l - 1) * DIM,
                zagg, N_NODES);
        }
        gemm_kernel<false><<<(N_NODES + 127) / 128, 512, 0, stream>>>(
            zagg, W1 + (size_t)l * DIM * DIM, b1 + l * DIM,
            nullptr, nullptr, nullptr, nullptr, sum1, ssq1, z1, N_NODES);
        gemm_kernel<true><<<(N_NODES + 127) / 128, 512, 0, stream>>>(
            z1, W2 + (size_t)l * DIM * DIM, b2 + l * DIM,
            sum1, ssq1, g1 + l * DIM, be1 + l * DIM, sum2, ssq2, z2buf, N_NODES);
    }
    {
        float* stp = stats + (size_t)(NLAYERS - 1) * 512;
        apply_final_kernel<<<((int)(N_NODES * D4) + 255) / 256, 256, 0, stream>>>(
            z2buf, stp + 256, stp + 384, og + (NLAYERS - 1) * DIM,
            ob + (NLAYERS - 1) * DIM, out, N_NODES * D4);
    }
}